// Round 4
// baseline (190.094 us; speedup 1.0000x reference)
//
#include <hip/hip_runtime.h>
#include <math.h>

#define NCAT  5
#define BATCH 64
#define ELEMS 196608          // C*H*W
#define P4    49152           // ELEMS/4 float4 positions
#define EPSV  1e-6f

#define P1_TPB 64
#define P1_NBLK 768           // 768*64 = 49152
#define P1_GRP 8

#define P2_PB  192            // position blocks: 192*256 = 49152
#define P2_SCH 8              // batch chunks
#define P2_CHB (BATCH / P2_SCH) // 8 batches per chunk
#define P2_NCOL (P2_PB * P2_SCH) // 1536 partial columns

// legacy fallback
#define NBLK 768
#define TPB  256
#define GRP  8

// ---------------- Phase 1: un-pass -----------------------------------------
// reads un (50 MB), writes rmap[5][P4] float4 = 1/(un_sum/safe_cnt + eps),
// and partials1[5][P1_NBLK] = per-block un sums.
__global__ __launch_bounds__(P1_TPB) void phase1_kernel(
    const float4* __restrict__ un,
    const int*    __restrict__ de_id,
    float4*       __restrict__ rmap,
    float*        __restrict__ partials1)
{
    __shared__ int   sh_de[BATCH];
    __shared__ float sh_inv[NCAT];

    const int tid = threadIdx.x;   // single 64-lane wave
    {
        int k = de_id[tid];
        sh_de[tid] = k;
        #pragma unroll
        for (int j = 0; j < NCAT; ++j) {
            unsigned long long m = __ballot(k == j);
            if (tid == j) {
                int c = __popcll(m);
                sh_inv[j] = 1.0f / (float)(c > 0 ? c : 1);
            }
        }
    }
    __syncthreads();

    const int p4 = blockIdx.x * P1_TPB + tid;
    const float4* up = un + p4;

    float4 un_s[NCAT];
    #pragma unroll
    for (int j = 0; j < NCAT; ++j) un_s[j] = make_float4(0.f, 0.f, 0.f, 0.f);

    float4 ub[2][P1_GRP];
    #pragma unroll
    for (int i = 0; i < P1_GRP; ++i) ub[0][i] = up[(size_t)i * P4];

    #pragma unroll
    for (int g = 0; g < BATCH / P1_GRP; ++g) {
        const int cur = g & 1, nxt = cur ^ 1;
        if (g < BATCH / P1_GRP - 1) {
            #pragma unroll
            for (int i = 0; i < P1_GRP; ++i)
                ub[nxt][i] = up[(size_t)((g + 1) * P1_GRP + i) * P4];
        }
        #pragma unroll
        for (int i = 0; i < P1_GRP; ++i) {
            float4 u = ub[cur][i];
            int k = sh_de[g * P1_GRP + i];
            #pragma unroll
            for (int j = 0; j < NCAT; ++j) {
                float m = (k == j) ? 1.0f : 0.0f;
                un_s[j].x = fmaf(m, u.x, un_s[j].x);
                un_s[j].y = fmaf(m, u.y, un_s[j].y);
                un_s[j].z = fmaf(m, u.z, un_s[j].z);
                un_s[j].w = fmaf(m, u.w, un_s[j].w);
            }
        }
    }

    float vals[NCAT];
    #pragma unroll
    for (int j = 0; j < NCAT; ++j) {
        float inv = sh_inv[j];
        float4 r;
        r.x = 1.0f / fmaf(un_s[j].x, inv, EPSV);
        r.y = 1.0f / fmaf(un_s[j].y, inv, EPSV);
        r.z = 1.0f / fmaf(un_s[j].z, inv, EPSV);
        r.w = 1.0f / fmaf(un_s[j].w, inv, EPSV);
        rmap[(size_t)j * P4 + p4] = r;
        vals[j] = un_s[j].x + un_s[j].y + un_s[j].z + un_s[j].w;
    }

    #pragma unroll
    for (int j = 0; j < NCAT; ++j) {
        float v = vals[j];
        #pragma unroll
        for (int off = 32; off >= 1; off >>= 1)
            v += __shfl_down(v, off, 64);
        if (tid == 0) partials1[j * P1_NBLK + blockIdx.x] = v;
    }
}

// ---------------- Phase 2: scaled-abs pass ----------------------------------
// grid (P2_PB, P2_SCH). reads restored+clean (101 MB) + rmap (hot),
// writes partials2[10][P2_NCOL]: rows 0..4 scaled sums, 5..9 abs sums.
__global__ __launch_bounds__(256) void phase2_kernel(
    const float4* __restrict__ restored,
    const float4* __restrict__ clean,
    const int*    __restrict__ de_id,
    const float4* __restrict__ rmap,
    float*        __restrict__ partials2)
{
    __shared__ int   sh_de[BATCH];
    __shared__ float sred[4][2 * NCAT];

    const int tid = threadIdx.x;
    if (tid < 64) sh_de[tid] = de_id[tid];
    __syncthreads();

    const int p4 = blockIdx.x * 256 + tid;
    const int b0 = blockIdx.y * P2_CHB;
    const float4* cp = clean + p4;
    const float4* rp = restored + p4;

    float4 ad4[NCAT];
    #pragma unroll
    for (int j = 0; j < NCAT; ++j) ad4[j] = make_float4(0.f, 0.f, 0.f, 0.f);

    // pipeline in pairs of batches: 4 float4 loads per stage
    float4 cb[2][2], rb[2][2];
    #pragma unroll
    for (int i = 0; i < 2; ++i) {
        const size_t off = (size_t)(b0 + i) * P4;
        cb[0][i] = cp[off];
        rb[0][i] = rp[off];
    }

    #pragma unroll
    for (int g = 0; g < P2_CHB / 2; ++g) {
        const int cur = g & 1, nxt = cur ^ 1;
        if (g < P2_CHB / 2 - 1) {
            #pragma unroll
            for (int i = 0; i < 2; ++i) {
                const size_t off = (size_t)(b0 + (g + 1) * 2 + i) * P4;
                cb[nxt][i] = cp[off];
                rb[nxt][i] = rp[off];
            }
        }
        #pragma unroll
        for (int i = 0; i < 2; ++i) {
            float4 c = cb[cur][i], r = rb[cur][i];
            float ax = fabsf(c.x - r.x);
            float ay = fabsf(c.y - r.y);
            float az = fabsf(c.z - r.z);
            float aw = fabsf(c.w - r.w);
            int k = sh_de[b0 + g * 2 + i];
            #pragma unroll
            for (int j = 0; j < NCAT; ++j) {
                float m = (k == j) ? 1.0f : 0.0f;
                ad4[j].x = fmaf(m, ax, ad4[j].x);
                ad4[j].y = fmaf(m, ay, ad4[j].y);
                ad4[j].z = fmaf(m, az, ad4[j].z);
                ad4[j].w = fmaf(m, aw, ad4[j].w);
            }
        }
    }

    float vals[2 * NCAT];
    #pragma unroll
    for (int j = 0; j < NCAT; ++j) {
        float4 m4 = rmap[(size_t)j * P4 + p4];
        vals[j] = ad4[j].x * m4.x + ad4[j].y * m4.y +
                  ad4[j].z * m4.z + ad4[j].w * m4.w;
        vals[NCAT + j] = ad4[j].x + ad4[j].y + ad4[j].z + ad4[j].w;
    }

    #pragma unroll
    for (int i = 0; i < 2 * NCAT; ++i) {
        float v = vals[i];
        #pragma unroll
        for (int off = 32; off >= 1; off >>= 1)
            v += __shfl_down(v, off, 64);
        vals[i] = v;
    }

    const int wave = tid >> 6, lane = tid & 63;
    if (lane == 0) {
        #pragma unroll
        for (int i = 0; i < 2 * NCAT; ++i) sred[wave][i] = vals[i];
    }
    __syncthreads();

    if (tid < 2 * NCAT) {
        float v = sred[0][tid] + sred[1][tid] + sred[2][tid] + sred[3][tid];
        const int col = blockIdx.y * P2_PB + blockIdx.x;
        partials2[tid * P2_NCOL + col] = v;
    }
}

// ---------------- Legacy single-pass (ws fallback) ---------------------------
__global__ __launch_bounds__(TPB) void accum_kernel(
    const float* __restrict__ restored,
    const float* __restrict__ clean,
    const int*   __restrict__ de_id,
    const float* __restrict__ un,
    float*       __restrict__ partials)
{
    __shared__ int   sh_de[BATCH];
    __shared__ float sh_inv[NCAT];
    __shared__ float sred[TPB / 64][3 * NCAT];

    const int tid = threadIdx.x;
    if (tid < 64) {
        int k = de_id[tid];
        sh_de[tid] = k;
        #pragma unroll
        for (int j = 0; j < NCAT; ++j) {
            unsigned long long m = __ballot(k == j);
            if (tid == j) {
                int c = __popcll(m);
                sh_inv[j] = 1.0f / (float)(c > 0 ? c : 1);
            }
        }
    }
    __syncthreads();

    const int p = blockIdx.x * TPB + tid;
    const float* rp = restored + p;
    const float* cp = clean + p;
    const float* up = un + p;

    float un_s[NCAT] = {0.f, 0.f, 0.f, 0.f, 0.f};
    float ad_s[NCAT] = {0.f, 0.f, 0.f, 0.f, 0.f};

    float ub[2][GRP], cb[2][GRP], rb[2][GRP];
    #pragma unroll
    for (int i = 0; i < GRP; ++i) {
        const size_t off = (size_t)i * ELEMS;
        ub[0][i] = up[off]; cb[0][i] = cp[off]; rb[0][i] = rp[off];
    }
    #pragma unroll
    for (int g = 0; g < BATCH / GRP; ++g) {
        const int cur = g & 1, nxt = cur ^ 1;
        if (g < BATCH / GRP - 1) {
            #pragma unroll
            for (int i = 0; i < GRP; ++i) {
                const size_t off = (size_t)((g + 1) * GRP + i) * ELEMS;
                ub[nxt][i] = up[off]; cb[nxt][i] = cp[off]; rb[nxt][i] = rp[off];
            }
        }
        #pragma unroll
        for (int i = 0; i < GRP; ++i) {
            float u  = ub[cur][i];
            float ad = fabsf(cb[cur][i] - rb[cur][i]);
            int   k  = sh_de[g * GRP + i];
            #pragma unroll
            for (int j = 0; j < NCAT; ++j) {
                float m = (k == j) ? 1.0f : 0.0f;
                un_s[j] = fmaf(m, u,  un_s[j]);
                ad_s[j] = fmaf(m, ad, ad_s[j]);
            }
        }
    }

    float vals[3 * NCAT];
    #pragma unroll
    for (int j = 0; j < NCAT; ++j) {
        float um = fmaf(un_s[j], sh_inv[j], EPSV);
        vals[j]            = ad_s[j] / um;
        vals[NCAT + j]     = ad_s[j];
        vals[2 * NCAT + j] = un_s[j];
    }
    #pragma unroll
    for (int i = 0; i < 3 * NCAT; ++i) {
        float v = vals[i];
        #pragma unroll
        for (int off = 32; off >= 1; off >>= 1)
            v += __shfl_down(v, off, 64);
        vals[i] = v;
    }
    const int wave = tid >> 6, lane = tid & 63;
    if (lane == 0) {
        #pragma unroll
        for (int i = 0; i < 3 * NCAT; ++i) sred[wave][i] = vals[i];
    }
    __syncthreads();
    if (tid < 3 * NCAT) {
        float v = sred[0][tid] + sred[1][tid] + sred[2][tid] + sred[3][tid];
        partials[tid * NBLK + blockIdx.x] = v;
    }
}

// ---------------- Epilogue ---------------------------------------------------
// rows 0..4 scaled, 5..9 abs from pSA[10][nA]; rows 10..14 un from pUN[5][nB].
__global__ __launch_bounds__(256) void epilogue_kernel(
    const int*   __restrict__ de_id,
    const float* __restrict__ pSA, int nA,
    const float* __restrict__ pUN, int nB,
    float*       __restrict__ out)
{
    __shared__ int   sh_cnt[NCAT];
    __shared__ float sh_acc[3 * NCAT];

    const int tid = threadIdx.x;
    if (tid < 64) {
        int k = de_id[tid];
        #pragma unroll
        for (int j = 0; j < NCAT; ++j) {
            unsigned long long m = __ballot(k == j);
            if (tid == j) sh_cnt[j] = __popcll(m);
        }
    }

    if (tid < 240) {
        const int row    = tid >> 4;
        const int lane16 = tid & 15;
        const float* base = (row < 10) ? (pSA + row * nA) : (pUN + (row - 10) * nB);
        const int n = (row < 10) ? nA : nB;
        float v = 0.f;
        for (int k = lane16; k < n; k += 16) v += base[k];
        v += __shfl_down(v, 8, 16);
        v += __shfl_down(v, 4, 16);
        v += __shfl_down(v, 2, 16);
        v += __shfl_down(v, 1, 16);
        if (lane16 == 0) sh_acc[row] = v;
    }
    __syncthreads();

    if (tid == 0) {
        const float Ef = (float)ELEMS;
        float cum_s = 0.f;
        long  cum_c = 0;
        float total = 0.f;
        int   num   = 0;
        float cat_losses[NCAT], old_loss[NCAT], bn[NCAT], unc_l1[NCAT];

        for (int j = 0; j < NCAT; ++j) {
            cum_s += sh_acc[j];
            cum_c += sh_cnt[j];
            float cum_elems = (float)cum_c * Ef;
            float cum_l1    = cum_s / fmaxf(cum_elems, 1.0f);

            bool  ne   = sh_cnt[j] > 0;
            float safe = (float)(ne ? sh_cnt[j] : 1);

            old_loss[j]  = ne ? sh_acc[NCAT + j] / (safe * Ef) : 0.f;
            float un_num = sh_acc[2 * NCAT + j] / (safe * Ef) + EPSV;
            bn[j]        = ne ? 2.0f * logf(un_num) : 0.f;
            unc_l1[j]    = ne ? cum_l1 : 0.f;
            cat_losses[j] = unc_l1[j] + bn[j];
            total += cat_losses[j];
            num   += ne ? 1 : 0;
        }
        total /= (float)num;

        out[0] = total;
        for (int j = 0; j < NCAT; ++j) {
            out[1 + j]  = cat_losses[j];
            out[6 + j]  = old_loss[j];
            out[11 + j] = bn[j];
            out[16 + j] = unc_l1[j];
        }
    }
}

extern "C" void kernel_launch(void* const* d_in, const int* in_sizes, int n_in,
                              void* d_out, int out_size, void* d_ws, size_t ws_size,
                              hipStream_t stream) {
    (void)in_sizes; (void)n_in; (void)out_size;
    const float* restored = (const float*)d_in[0];
    const float* clean    = (const float*)d_in[1];
    const int*   de_id    = (const int*)d_in[2];
    const float* un       = (const float*)d_in[3];
    float* out = (float*)d_out;

    // ws layout (new path): rmap[5][P4] float4 | partials1[5][768] | partials2[10][1536]
    const size_t rmap_bytes = (size_t)NCAT * P4 * sizeof(float4);
    const size_t p1_bytes   = (size_t)NCAT * P1_NBLK * sizeof(float);
    const size_t p2_bytes   = (size_t)2 * NCAT * P2_NCOL * sizeof(float);

    if (ws_size >= rmap_bytes + p1_bytes + p2_bytes) {
        float4* rmap      = (float4*)d_ws;
        float*  partials1 = (float*)((char*)d_ws + rmap_bytes);
        float*  partials2 = (float*)((char*)d_ws + rmap_bytes + p1_bytes);

        phase1_kernel<<<P1_NBLK, P1_TPB, 0, stream>>>(
            (const float4*)un, de_id, rmap, partials1);
        phase2_kernel<<<dim3(P2_PB, P2_SCH), 256, 0, stream>>>(
            (const float4*)restored, (const float4*)clean, de_id,
            (const float4*)rmap, partials2);
        epilogue_kernel<<<1, 256, 0, stream>>>(
            de_id, partials2, P2_NCOL, partials1, P1_NBLK, out);
    } else {
        float* partials = (float*)d_ws;   // [15][768]
        accum_kernel<<<NBLK, TPB, 0, stream>>>(restored, clean, de_id, un, partials);
        epilogue_kernel<<<1, 256, 0, stream>>>(
            de_id, partials, NBLK, partials + 10 * NBLK, NBLK, out);
    }
}

// Round 5
// 174.831 us; speedup vs baseline: 1.0873x; 1.0873x over previous
//
#include <hip/hip_runtime.h>
#include <math.h>

#define NCAT  5
#define BATCH 64
#define ELEMS 196608          // C*H*W
#define P4    49152           // ELEMS/4 float4 positions
#define NBLK  768             // blocks: 768 * 64 float4-positions = 49152
#define EPSV  1e-6f

// d_ws layout: partials[15][NBLK] floats.
// rows 0..4 = scaled sums, 5..9 = abs sums, 10..14 = un sums
//
// Wave layout: lane = grp*16 + posl. 16 float4 positions per wave, 4 batch
// groups of 16 batches each. un partials are combined across groups with
// shfl_xor(16|32) before the per-position division; ad partials are scaled
// after (linear), so the single pass preserves exact reference semantics.
__global__ __launch_bounds__(256) void accum_kernel(
    const float4* __restrict__ restored,
    const float4* __restrict__ clean,
    const int*    __restrict__ de_id,
    const float4* __restrict__ un,
    float*        __restrict__ partials)
{
    __shared__ int   sh_de[BATCH];
    __shared__ float sh_inv[NCAT];
    __shared__ float sred[4][3 * NCAT];

    const int tid = threadIdx.x;

    if (tid < 64) {
        int k = de_id[tid];
        sh_de[tid] = k;
        #pragma unroll
        for (int j = 0; j < NCAT; ++j) {
            unsigned long long m = __ballot(k == j);
            if (tid == j) {
                int c = __popcll(m);
                sh_inv[j] = 1.0f / (float)(c > 0 ? c : 1);
            }
        }
    }
    __syncthreads();

    const int lane = tid & 63;
    const int wave = tid >> 6;
    const int grp  = lane >> 4;          // batch group 0..3
    const int posl = lane & 15;          // position within wave
    const int p4   = blockIdx.x * 64 + wave * 16 + posl;
    const int b0   = grp * 16;           // first batch for this thread

    const float4* rp = restored + p4;
    const float4* cp = clean + p4;
    const float4* up = un + p4;

    float4 un_s[NCAT], ad_s[NCAT];
    #pragma unroll
    for (int j = 0; j < NCAT; ++j) {
        un_s[j] = make_float4(0.f, 0.f, 0.f, 0.f);
        ad_s[j] = make_float4(0.f, 0.f, 0.f, 0.f);
    }

    // double-buffered pipeline: stages of 4 batches (12 float4 loads/stage)
    float4 ub[2][4], cb[2][4], rb[2][4];
    #pragma unroll
    for (int i = 0; i < 4; ++i) {
        const size_t off = (size_t)(b0 + i) * P4;
        ub[0][i] = up[off];
        cb[0][i] = cp[off];
        rb[0][i] = rp[off];
    }

    #pragma unroll
    for (int st = 0; st < 4; ++st) {
        const int cur = st & 1, nxt = cur ^ 1;
        if (st < 3) {
            #pragma unroll
            for (int i = 0; i < 4; ++i) {
                const size_t off = (size_t)(b0 + (st + 1) * 4 + i) * P4;
                ub[nxt][i] = up[off];
                cb[nxt][i] = cp[off];
                rb[nxt][i] = rp[off];
            }
        }
        #pragma unroll
        for (int i = 0; i < 4; ++i) {
            float4 u = ub[cur][i];
            float4 c = cb[cur][i];
            float4 r = rb[cur][i];
            float ax = fabsf(c.x - r.x);
            float ay = fabsf(c.y - r.y);
            float az = fabsf(c.z - r.z);
            float aw = fabsf(c.w - r.w);
            int k = sh_de[b0 + st * 4 + i];
            #pragma unroll
            for (int j = 0; j < NCAT; ++j) {
                float m = (k == j) ? 1.0f : 0.0f;
                un_s[j].x = fmaf(m, u.x, un_s[j].x);
                un_s[j].y = fmaf(m, u.y, un_s[j].y);
                un_s[j].z = fmaf(m, u.z, un_s[j].z);
                un_s[j].w = fmaf(m, u.w, un_s[j].w);
                ad_s[j].x = fmaf(m, ax, ad_s[j].x);
                ad_s[j].y = fmaf(m, ay, ad_s[j].y);
                ad_s[j].z = fmaf(m, az, ad_s[j].z);
                ad_s[j].w = fmaf(m, aw, ad_s[j].w);
            }
        }
    }

    float vals[3 * NCAT];
    #pragma unroll
    for (int j = 0; j < NCAT; ++j) {
        // raw un contribution: pre-combine partial (avoids double counting)
        vals[2 * NCAT + j] = un_s[j].x + un_s[j].y + un_s[j].z + un_s[j].w;

        // combine un across the 4 batch groups → full 64-batch sum per pos
        float sx = un_s[j].x, sy = un_s[j].y, sz = un_s[j].z, sw = un_s[j].w;
        sx += __shfl_xor(sx, 16, 64);  sx += __shfl_xor(sx, 32, 64);
        sy += __shfl_xor(sy, 16, 64);  sy += __shfl_xor(sy, 32, 64);
        sz += __shfl_xor(sz, 16, 64);  sz += __shfl_xor(sz, 32, 64);
        sw += __shfl_xor(sw, 16, 64);  sw += __shfl_xor(sw, 32, 64);

        const float inv = sh_inv[j];
        float rx = 1.0f / fmaf(sx, inv, EPSV);
        float ry = 1.0f / fmaf(sy, inv, EPSV);
        float rz = 1.0f / fmaf(sz, inv, EPSV);
        float rw = 1.0f / fmaf(sw, inv, EPSV);

        vals[j] = ad_s[j].x * rx + ad_s[j].y * ry +
                  ad_s[j].z * rz + ad_s[j].w * rw;
        vals[NCAT + j] = ad_s[j].x + ad_s[j].y + ad_s[j].z + ad_s[j].w;
    }

    // 64-lane butterfly reduction of all 15 values
    #pragma unroll
    for (int i = 0; i < 3 * NCAT; ++i) {
        float v = vals[i];
        #pragma unroll
        for (int off = 32; off >= 1; off >>= 1)
            v += __shfl_down(v, off, 64);
        vals[i] = v;
    }

    if (lane == 0) {
        #pragma unroll
        for (int i = 0; i < 3 * NCAT; ++i) sred[wave][i] = vals[i];
    }
    __syncthreads();

    if (tid < 3 * NCAT) {
        float v = sred[0][tid] + sred[1][tid] + sred[2][tid] + sred[3][tid];
        partials[tid * NBLK + blockIdx.x] = v;   // transposed: row-contiguous
    }
}

// 1 block, 256 threads: reduce partials[15][NBLK] + final 21-output math
__global__ __launch_bounds__(256) void epilogue_kernel(
    const int*   __restrict__ de_id,
    const float* __restrict__ partials,
    float*       __restrict__ out)
{
    __shared__ int   sh_cnt[NCAT];
    __shared__ float sh_acc[3 * NCAT];

    const int tid = threadIdx.x;
    if (tid < 64) {
        int k = de_id[tid];
        #pragma unroll
        for (int j = 0; j < NCAT; ++j) {
            unsigned long long m = __ballot(k == j);
            if (tid == j) sh_cnt[j] = __popcll(m);
        }
    }

    if (tid < 240) {
        const int row    = tid >> 4;
        const int lane16 = tid & 15;
        float v = 0.f;
        #pragma unroll 4
        for (int k = 0; k < NBLK / 16; ++k)
            v += partials[row * NBLK + lane16 + (k << 4)];
        v += __shfl_down(v, 8, 16);
        v += __shfl_down(v, 4, 16);
        v += __shfl_down(v, 2, 16);
        v += __shfl_down(v, 1, 16);
        if (lane16 == 0) sh_acc[row] = v;
    }
    __syncthreads();

    if (tid == 0) {
        const float Ef = (float)ELEMS;
        float cum_s = 0.f;
        long  cum_c = 0;
        float total = 0.f;
        int   num   = 0;
        float cat_losses[NCAT], old_loss[NCAT], bn[NCAT], unc_l1[NCAT];

        for (int j = 0; j < NCAT; ++j) {
            cum_s += sh_acc[j];
            cum_c += sh_cnt[j];
            float cum_elems = (float)cum_c * Ef;
            float cum_l1    = cum_s / fmaxf(cum_elems, 1.0f);

            bool  ne   = sh_cnt[j] > 0;
            float safe = (float)(ne ? sh_cnt[j] : 1);

            old_loss[j]  = ne ? sh_acc[NCAT + j] / (safe * Ef) : 0.f;
            float un_num = sh_acc[2 * NCAT + j] / (safe * Ef) + EPSV;
            bn[j]        = ne ? 2.0f * logf(un_num) : 0.f;
            unc_l1[j]    = ne ? cum_l1 : 0.f;
            cat_losses[j] = unc_l1[j] + bn[j];
            total += cat_losses[j];
            num   += ne ? 1 : 0;
        }
        total /= (float)num;

        out[0] = total;
        for (int j = 0; j < NCAT; ++j) {
            out[1 + j]  = cat_losses[j];
            out[6 + j]  = old_loss[j];
            out[11 + j] = bn[j];
            out[16 + j] = unc_l1[j];
        }
    }
}

extern "C" void kernel_launch(void* const* d_in, const int* in_sizes, int n_in,
                              void* d_out, int out_size, void* d_ws, size_t ws_size,
                              hipStream_t stream) {
    (void)in_sizes; (void)n_in; (void)out_size; (void)ws_size;
    const float4* restored = (const float4*)d_in[0];
    const float4* clean    = (const float4*)d_in[1];
    const int*    de_id    = (const int*)d_in[2];
    const float4* un       = (const float4*)d_in[3];
    float* out      = (float*)d_out;
    float* partials = (float*)d_ws;   // [15][NBLK] — fully overwritten, no init needed

    accum_kernel<<<NBLK, 256, 0, stream>>>(restored, clean, de_id, un, partials);
    epilogue_kernel<<<1, 256, 0, stream>>>(de_id, partials, out);
}